// Round 2
// baseline (3266.689 us; speedup 1.0000x reference)
//
#include <hip/hip_runtime.h>

// Problem constants (B=2, S=2048, D=1024, H=16, HD=64). fp32 in / fp32 out.
#define NB 2
#define NS 2048
#define ND 1024
#define NH 16
#define NHD 64
#define QLD (3 * ND)   // qkv workspace row stride = 3072

// C[M,N] = A[M,K] @ W[K,N] + bias[N], all fp32.
// 64x64 block tile, 256 threads, 4x4 microtile, BK=16.
__global__ __launch_bounds__(256) void gemm_bias_kernel(
    const float* __restrict__ A, const float* __restrict__ W,
    const float* __restrict__ bias, float* __restrict__ C,
    int M, int N, int K)
{
    __shared__ float As[16][68];   // [k][row], pad 68: float4-aligned rows, conflict-free
    __shared__ float Bs[16][64];   // [k][col]
    const int tid = threadIdx.x;
    const int tx = tid & 15, ty = tid >> 4;
    const int row0 = blockIdx.y << 6, col0 = blockIdx.x << 6;
    const int ar = tid >> 2, ac = (tid & 3) << 2;   // A load: row ar, cols ac..ac+3
    const int br = tid >> 4, bc = (tid & 15) << 2;  // W load: row br, cols bc..bc+3

    float acc[4][4] = {{0.f}};

    const float* Ap = A + (size_t)(row0 + ar) * K + ac;
    const float* Wp = W + (size_t)br * N + col0 + bc;

    for (int kk = 0; kk < K; kk += 16) {
        float4 av = *(const float4*)(Ap + kk);
        float4 wv = *(const float4*)(Wp + (size_t)kk * N);
        __syncthreads();   // previous iteration's LDS reads done
        As[ac + 0][ar] = av.x;
        As[ac + 1][ar] = av.y;
        As[ac + 2][ar] = av.z;
        As[ac + 3][ar] = av.w;
        *(float4*)&Bs[br][bc] = wv;
        __syncthreads();
        #pragma unroll
        for (int k = 0; k < 16; ++k) {
            float4 a4 = *(const float4*)&As[k][ty << 2];
            float4 b4 = *(const float4*)&Bs[k][tx << 2];
            float as[4] = {a4.x, a4.y, a4.z, a4.w};
            float bs[4] = {b4.x, b4.y, b4.z, b4.w};
            #pragma unroll
            for (int i = 0; i < 4; ++i)
                #pragma unroll
                for (int j = 0; j < 4; ++j)
                    acc[i][j] += as[i] * bs[j];
        }
    }

    float4 bj = *(const float4*)(bias + col0 + (tx << 2));
    #pragma unroll
    for (int i = 0; i < 4; ++i) {
        size_t off = (size_t)(row0 + (ty << 2) + i) * N + col0 + (tx << 2);
        float4 o = make_float4(acc[i][0] + bj.x, acc[i][1] + bj.y,
                               acc[i][2] + bj.z, acc[i][3] + bj.w);
        *(float4*)(C + off) = o;
    }
}

// One wave (64 threads) per (b, h, query-row). Online softmax over causal keys
// in chunks of 64. Lane d owns output dim d. Never materializes S x S scores;
// the causal mask is applied analytically (mask input unused).
// qkv layout: [B*S, 3072]; head h: q at col h*192, k at +64, v at +128.
__global__ __launch_bounds__(64) void attn_kernel(
    const float* __restrict__ qkv, float* __restrict__ vals)
{
    __shared__ float Ks[64][68];   // [key][d], pad 68
    __shared__ float q_s[64];
    __shared__ float p_s[64];
    const int lane = threadIdx.x;
    const int qi = blockIdx.x;
    const int bh = blockIdx.y;
    const int b = bh >> 4, h = bh & 15;
    const size_t base_bh = (size_t)b * NS * QLD + (size_t)h * (3 * NHD);

    // q scaled by 1/sqrt(HD)=1/8 up front
    q_s[lane] = qkv[base_bh + (size_t)qi * QLD + lane] * 0.125f;

    float o = 0.f, m = -INFINITY, l = 0.f;
    const int nchunk = (qi >> 6) + 1;
    for (int c = 0; c < nchunk; ++c) {
        const int kbase = c << 6;
        __syncthreads();  // q_s visible (c=0); prev chunk's Ks/p_s reads done
        // stage K chunk: lane loads key row (kbase+lane), 64 floats = 16 x float4
        const float* krow = qkv + base_bh + (size_t)(kbase + lane) * QLD + NHD;
        #pragma unroll
        for (int v = 0; v < 16; ++v)
            *(float4*)&Ks[lane][v << 2] = *(const float4*)(krow + (v << 2));
        __syncthreads();

        const int key = kbase + lane;
        float s = -INFINITY;
        if (key <= qi) {
            float acc = 0.f;
            #pragma unroll
            for (int d4 = 0; d4 < 64; d4 += 4) {
                float4 q4 = *(const float4*)&q_s[d4];
                float4 k4 = *(const float4*)&Ks[lane][d4];
                acc += q4.x * k4.x + q4.y * k4.y + q4.z * k4.z + q4.w * k4.w;
            }
            s = acc;
        }
        // wave max of s
        float cmax = s;
        #pragma unroll
        for (int off = 32; off > 0; off >>= 1)
            cmax = fmaxf(cmax, __shfl_xor(cmax, off, 64));
        const float m_new = fmaxf(m, cmax);
        const float alpha = __expf(m - m_new);   // exp(-inf)=0 handles first chunk
        const float p = (key <= qi) ? __expf(s - m_new) : 0.f;
        float psum = p;
        #pragma unroll
        for (int off = 32; off > 0; off >>= 1)
            psum += __shfl_xor(psum, off, 64);
        l = l * alpha + psum;
        o *= alpha;
        m = m_new;
        p_s[lane] = p;
        __syncthreads();
        // o_d += sum_j p_j * V[kbase+j][d]; lane=d -> coalesced V reads
        const float* vp = qkv + base_bh + (size_t)kbase * QLD + 2 * NHD + lane;
        float oacc = 0.f;
        #pragma unroll 8
        for (int j = 0; j < 64; ++j)
            oacc += p_s[j] * vp[(size_t)j * QLD];
        o += oacc;
    }
    // vals layout [B, S, H*HD] = [B,S,D] (matches transpose(0,2,1,3).reshape)
    vals[((size_t)b * NS + qi) * ND + h * NHD + lane] = o / l;
}

extern "C" void kernel_launch(void* const* d_in, const int* in_sizes, int n_in,
                              void* d_out, int out_size, void* d_ws, size_t ws_size,
                              hipStream_t stream)
{
    // setup_inputs order: x, mask(unused - causal applied analytically),
    //                     W_qkv, b_qkv, W_o, b_o   -- all fp32
    const float* x    = (const float*)d_in[0];
    const float* Wqkv = (const float*)d_in[2];
    const float* bqkv = (const float*)d_in[3];
    const float* Wo   = (const float*)d_in[4];
    const float* bo   = (const float*)d_in[5];
    float* out = (float*)d_out;

    // workspace: qkv [4096,3072] f32 (50.3 MB) + vals [4096,1024] f32 (16.8 MB)
    float* qkv  = (float*)d_ws;
    float* vals = qkv + (size_t)NB * NS * QLD;

    const int M = NB * NS;  // 4096
    gemm_bias_kernel<<<dim3(QLD / 64, M / 64), dim3(256), 0, stream>>>(
        x, Wqkv, bqkv, qkv, M, QLD, ND);
    attn_kernel<<<dim3(NS, NB * NH), dim3(64), 0, stream>>>(qkv, vals);
    gemm_bias_kernel<<<dim3(ND / 64, M / 64), dim3(256), 0, stream>>>(
        vals, Wo, bo, out, M, ND, ND);
}

// Round 3
// 681.294 us; speedup vs baseline: 4.7948x; 4.7948x over previous
//
#include <hip/hip_runtime.h>

// Problem constants (B=2, S=2048, D=1024, H=16, HD=64). fp32 in / fp32 out.
#define NB 2
#define NS 2048
#define ND 1024
#define NH 16
#define NHD 64
#define QLD (3 * ND)   // qkv workspace row stride = 3072
#define PAD 72         // LDS row stride (bf16 elems) for 64-wide tiles

typedef unsigned short u16;
typedef __attribute__((ext_vector_type(8))) short short8;   // 8 x bf16 (4 VGPRs)
typedef __attribute__((ext_vector_type(4))) float f32x4;

__device__ __forceinline__ u16 f2b(float f) {
    unsigned int x = __float_as_uint(f);
    return (u16)((x + 0x7fffu + ((x >> 16) & 1u)) >> 16);  // RNE
}

// ---------------------------------------------------------------------------
// C[M,N] = A[M,K] @ W[K,N] + bias[N], all fp32. (unchanged from R1 - passed)
// 64x64 block tile, 256 threads, 4x4 microtile, BK=16.
__global__ __launch_bounds__(256) void gemm_bias_kernel(
    const float* __restrict__ A, const float* __restrict__ W,
    const float* __restrict__ bias, float* __restrict__ C,
    int M, int N, int K)
{
    __shared__ float As[16][68];
    __shared__ float Bs[16][64];
    const int tid = threadIdx.x;
    const int tx = tid & 15, ty = tid >> 4;
    const int row0 = blockIdx.y << 6, col0 = blockIdx.x << 6;
    const int ar = tid >> 2, ac = (tid & 3) << 2;
    const int br = tid >> 4, bc = (tid & 15) << 2;

    float acc[4][4] = {{0.f}};

    const float* Ap = A + (size_t)(row0 + ar) * K + ac;
    const float* Wp = W + (size_t)br * N + col0 + bc;

    for (int kk = 0; kk < K; kk += 16) {
        float4 av = *(const float4*)(Ap + kk);
        float4 wv = *(const float4*)(Wp + (size_t)kk * N);
        __syncthreads();
        As[ac + 0][ar] = av.x;
        As[ac + 1][ar] = av.y;
        As[ac + 2][ar] = av.z;
        As[ac + 3][ar] = av.w;
        *(float4*)&Bs[br][bc] = wv;
        __syncthreads();
        #pragma unroll
        for (int k = 0; k < 16; ++k) {
            float4 a4 = *(const float4*)&As[k][ty << 2];
            float4 b4 = *(const float4*)&Bs[k][tx << 2];
            float as[4] = {a4.x, a4.y, a4.z, a4.w};
            float bs[4] = {b4.x, b4.y, b4.z, b4.w};
            #pragma unroll
            for (int i = 0; i < 4; ++i)
                #pragma unroll
                for (int j = 0; j < 4; ++j)
                    acc[i][j] += as[i] * bs[j];
        }
    }

    float4 bj = *(const float4*)(bias + col0 + (tx << 2));
    #pragma unroll
    for (int i = 0; i < 4; ++i) {
        size_t off = (size_t)(row0 + (ty << 2) + i) * N + col0 + (tx << 2);
        float4 o = make_float4(acc[i][0] + bj.x, acc[i][1] + bj.y,
                               acc[i][2] + bj.z, acc[i][3] + bj.w);
        *(float4*)(C + off) = o;
    }
}

// ---------------------------------------------------------------------------
// MFMA flash attention. Block = (qt, bh): 64-query tile of head (b,h).
// 4 waves x 16-query strips. K/V tiles of 64 keys, causal (kt <= qt).
// mfma_f32_16x16x32_bf16: A[m=lane&15][k=quad*8+j], B[k=quad*8+j][n=lane&15],
// C/D col=lane&15, row=quad*4+reg  (quad = lane>>4).
// P round-trips through LDS (C-layout -> A-layout); V staged transposed.
__global__ __launch_bounds__(256) void attn_kernel(
    const float* __restrict__ qkv, float* __restrict__ vals)
{
    __shared__ u16 Qs[64 * PAD];   // [q_local][d]
    __shared__ u16 Ks[64 * PAD];   // [k_local][d]
    __shared__ u16 Vt[64 * PAD];   // [d][k_local]  (transposed)
    __shared__ u16 Ps[64 * PAD];   // [q_local][k_local], per-wave 16-row strips

    const int tid = threadIdx.x;
    const int wave = tid >> 6, lane = tid & 63;
    const int col = lane & 15, quad = lane >> 4;
    const int qt = blockIdx.x;     // query tile 0..31
    const int bh = blockIdx.y;     // 0..31
    const int b = bh >> 4, h = bh & 15;
    const size_t base = (size_t)b * NS * QLD + (size_t)h * (3 * NHD);

    // ---- stage Q tile (64 x 64) fp32 -> bf16, once ----
    {
        const int r = tid >> 2, c0 = (tid & 3) << 4;
        const float* src = qkv + base + (size_t)(qt * 64 + r) * QLD + c0;
        u16* dst = &Qs[r * PAD + c0];
        #pragma unroll
        for (int j = 0; j < 4; ++j) {
            float4 v = *(const float4*)(src + 4 * j);
            *(ushort4*)(dst + 4 * j) =
                make_ushort4(f2b(v.x), f2b(v.y), f2b(v.z), f2b(v.w));
        }
    }

    short8 aq0, aq1;               // hoisted Q A-fragments (d-halves)
    f32x4 accO[4] = {};            // O accumulator, 4 d-groups (C-layout)
    float mrow[4], lrow[4], alpha[4];
    #pragma unroll
    for (int r = 0; r < 4; ++r) { mrow[r] = -1e30f; lrow[r] = 0.f; }

    const int q0 = wave * 16;      // this wave's query strip (local)

    for (int kt = 0; kt <= qt; ++kt) {
        __syncthreads();           // Qs visible (kt=0); prior Ks/Vt reads done
        // ---- stage K tile ----
        {
            const int r = tid >> 2, c0 = (tid & 3) << 4;
            const float* src = qkv + base + (size_t)(kt * 64 + r) * QLD + NHD + c0;
            u16* dst = &Ks[r * PAD + c0];
            #pragma unroll
            for (int j = 0; j < 4; ++j) {
                float4 v = *(const float4*)(src + 4 * j);
                *(ushort4*)(dst + 4 * j) =
                    make_ushort4(f2b(v.x), f2b(v.y), f2b(v.z), f2b(v.w));
            }
        }
        // ---- stage V tile transposed (4x4 register transpose) ----
        {
            const int tx = tid & 15, ty = tid >> 4;
            const int k0 = ty << 2, d0 = tx << 2;
            const float* vsrc = qkv + base + (size_t)(kt * 64 + k0) * QLD + 2 * NHD + d0;
            float4 r0 = *(const float4*)(vsrc);
            float4 r1 = *(const float4*)(vsrc + QLD);
            float4 r2 = *(const float4*)(vsrc + 2 * QLD);
            float4 r3 = *(const float4*)(vsrc + 3 * QLD);
            *(ushort4*)&Vt[(d0 + 0) * PAD + k0] =
                make_ushort4(f2b(r0.x), f2b(r1.x), f2b(r2.x), f2b(r3.x));
            *(ushort4*)&Vt[(d0 + 1) * PAD + k0] =
                make_ushort4(f2b(r0.y), f2b(r1.y), f2b(r2.y), f2b(r3.y));
            *(ushort4*)&Vt[(d0 + 2) * PAD + k0] =
                make_ushort4(f2b(r0.z), f2b(r1.z), f2b(r2.z), f2b(r3.z));
            *(ushort4*)&Vt[(d0 + 3) * PAD + k0] =
                make_ushort4(f2b(r0.w), f2b(r1.w), f2b(r2.w), f2b(r3.w));
        }
        __syncthreads();

        if (kt == 0) {
            aq0 = *(const short8*)&Qs[(q0 + col) * PAD + quad * 8];
            aq1 = *(const short8*)&Qs[(q0 + col) * PAD + 32 + quad * 8];
        }

        // ---- S = Q K^T (16q x 64k per wave) ----
        f32x4 s[4] = {};
        #pragma unroll
        for (int kg = 0; kg < 4; ++kg) {
            short8 b0 = *(const short8*)&Ks[(kg * 16 + col) * PAD + quad * 8];
            short8 b1 = *(const short8*)&Ks[(kg * 16 + col) * PAD + 32 + quad * 8];
            s[kg] = __builtin_amdgcn_mfma_f32_16x16x32_bf16(aq0, b0, s[kg], 0, 0, 0);
            s[kg] = __builtin_amdgcn_mfma_f32_16x16x32_bf16(aq1, b1, s[kg], 0, 0, 0);
        }

        // ---- scale + causal mask (diagonal tile only) ----
        const bool diag = (kt == qt);
        #pragma unroll
        for (int kg = 0; kg < 4; ++kg)
            #pragma unroll
            for (int r = 0; r < 4; ++r) {
                float v = s[kg][r] * 0.125f;   // 1/sqrt(HD)
                if (diag && (kg * 16 + col > q0 + quad * 4 + r)) v = -1e30f;
                s[kg][r] = v;
            }

        // ---- online softmax (row = quad*4+r across 16-lane groups) ----
        #pragma unroll
        for (int r = 0; r < 4; ++r) {
            float mx = fmaxf(fmaxf(s[0][r], s[1][r]), fmaxf(s[2][r], s[3][r]));
            mx = fmaxf(mx, __shfl_xor(mx, 1, 64));
            mx = fmaxf(mx, __shfl_xor(mx, 2, 64));
            mx = fmaxf(mx, __shfl_xor(mx, 4, 64));
            mx = fmaxf(mx, __shfl_xor(mx, 8, 64));
            float mn = fmaxf(mrow[r], mx);
            alpha[r] = __expf(mrow[r] - mn);
            mrow[r] = mn;
        }
        #pragma unroll
        for (int r = 0; r < 4; ++r) {
            float ps = 0.f;
            #pragma unroll
            for (int kg = 0; kg < 4; ++kg) {
                float p = __expf(s[kg][r] - mrow[r]);  // masked -> exp(-huge)=0
                ps += p;
                Ps[(q0 + quad * 4 + r) * PAD + kg * 16 + col] = f2b(p);
            }
            ps += __shfl_xor(ps, 1, 64);
            ps += __shfl_xor(ps, 2, 64);
            ps += __shfl_xor(ps, 4, 64);
            ps += __shfl_xor(ps, 8, 64);
            lrow[r] = lrow[r] * alpha[r] + ps;
            #pragma unroll
            for (int dg = 0; dg < 4; ++dg) accO[dg][r] *= alpha[r];
        }

        // ---- O += P V (per-wave private Ps strip; no barrier needed) ----
        short8 ap0 = *(const short8*)&Ps[(q0 + col) * PAD + quad * 8];
        short8 ap1 = *(const short8*)&Ps[(q0 + col) * PAD + 32 + quad * 8];
        #pragma unroll
        for (int dg = 0; dg < 4; ++dg) {
            short8 b0 = *(const short8*)&Vt[(dg * 16 + col) * PAD + quad * 8];
            short8 b1 = *(const short8*)&Vt[(dg * 16 + col) * PAD + 32 + quad * 8];
            accO[dg] = __builtin_amdgcn_mfma_f32_16x16x32_bf16(ap0, b0, accO[dg], 0, 0, 0);
            accO[dg] = __builtin_amdgcn_mfma_f32_16x16x32_bf16(ap1, b1, accO[dg], 0, 0, 0);
        }
    }

    // ---- epilogue: vals[b][q][h*64+d] = O / l ----
    #pragma unroll
    for (int r = 0; r < 4; ++r) {
        const float inv = 1.f / lrow[r];
        const size_t rowoff =
            ((size_t)b * NS + qt * 64 + q0 + quad * 4 + r) * ND + h * NHD;
        #pragma unroll
        for (int dg = 0; dg < 4; ++dg)
            vals[rowoff + dg * 16 + col] = accO[dg][r] * inv;
    }
}

extern "C" void kernel_launch(void* const* d_in, const int* in_sizes, int n_in,
                              void* d_out, int out_size, void* d_ws, size_t ws_size,
                              hipStream_t stream)
{
    // setup_inputs order: x, mask(unused - causal applied analytically),
    //                     W_qkv, b_qkv, W_o, b_o   -- all fp32
    const float* x    = (const float*)d_in[0];
    const float* Wqkv = (const float*)d_in[2];
    const float* bqkv = (const float*)d_in[3];
    const float* Wo   = (const float*)d_in[4];
    const float* bo   = (const float*)d_in[5];
    float* out = (float*)d_out;

    // workspace: qkv [4096,3072] f32 (50.3 MB) + vals [4096,1024] f32 (16.8 MB)
    float* qkv  = (float*)d_ws;
    float* vals = qkv + (size_t)NB * NS * QLD;

    const int M = NB * NS;  // 4096
    gemm_bias_kernel<<<dim3(QLD / 64, M / 64), dim3(256), 0, stream>>>(
        x, Wqkv, bqkv, qkv, M, QLD, ND);
    attn_kernel<<<dim3(32, NB * NH), dim3(256), 0, stream>>>(qkv, vals);
    gemm_bias_kernel<<<dim3(ND / 64, M / 64), dim3(256), 0, stream>>>(
        vals, Wo, bo, out, M, ND, ND);
}

// Round 4
// 292.059 us; speedup vs baseline: 11.1850x; 2.3327x over previous
//
#include <hip/hip_runtime.h>

// Problem constants (B=2, S=2048, D=1024, H=16, HD=64). fp32 in / fp32 out.
#define NB 2
#define NS 2048
#define ND 1024
#define NH 16
#define NHD 64
#define QLD (3 * ND)   // qkv workspace row stride in elements = 3072
#define PAD 72         // LDS row stride (bf16 elems) for 64-wide attn tiles

typedef unsigned short u16;
typedef __attribute__((ext_vector_type(8))) short short8;   // 8 x bf16 (4 VGPRs)
typedef __attribute__((ext_vector_type(4))) float f32x4;

__device__ __forceinline__ u16 f2b(float f) {
    unsigned int x = __float_as_uint(f);
    return (u16)((x + 0x7fffu + ((x >> 16) & 1u)) >> 16);  // RNE
}

// ---------------------------------------------------------------------------
// fp32 -> bf16 elementwise cast (for x). n must be a multiple of 8.
__global__ __launch_bounds__(256) void convert_bf16(
    const float* __restrict__ src, u16* __restrict__ dst, int n)
{
    const int i = (blockIdx.x * 256 + threadIdx.x) * 8;
    if (i >= n) return;
    float4 a = *(const float4*)(src + i);
    float4 b = *(const float4*)(src + i + 4);
    *(ushort4*)(dst + i)     = make_ushort4(f2b(a.x), f2b(a.y), f2b(a.z), f2b(a.w));
    *(ushort4*)(dst + i + 4) = make_ushort4(f2b(b.x), f2b(b.y), f2b(b.z), f2b(b.w));
}

// ---------------------------------------------------------------------------
// W[K,N] fp32 -> WT[N,K] bf16 (64x64 tiles via LDS).
__global__ __launch_bounds__(256) void transpose_bf16(
    const float* __restrict__ W, u16* __restrict__ WT, int K, int N)
{
    __shared__ u16 Ts[64 * 72];    // [n][k], pad 72 keeps 16B alignment
    const int t = threadIdx.x;
    const int k0 = blockIdx.y << 6, n0 = blockIdx.x << 6;
    const int r = t >> 4, c = (t & 15) << 2;
    #pragma unroll
    for (int rr = 0; rr < 64; rr += 16) {
        float4 v = *(const float4*)&W[(size_t)(k0 + r + rr) * N + n0 + c];
        Ts[(c + 0) * 72 + r + rr] = f2b(v.x);
        Ts[(c + 1) * 72 + r + rr] = f2b(v.y);
        Ts[(c + 2) * 72 + r + rr] = f2b(v.z);
        Ts[(c + 3) * 72 + r + rr] = f2b(v.w);
    }
    __syncthreads();
    const int n = t >> 2, cc = (t & 3) << 4;
    uint4 a = *(const uint4*)&Ts[n * 72 + cc];
    uint4 b = *(const uint4*)&Ts[n * 72 + cc + 8];
    *(uint4*)&WT[(size_t)(n0 + n) * K + k0 + cc]     = a;
    *(uint4*)&WT[(size_t)(n0 + n) * K + k0 + cc + 8] = b;
}

// ---------------------------------------------------------------------------
// bf16 MFMA GEMM (m97 structure): C[M,N] = A[M,K] @ BT[N,K]^T + bias[N].
// 128x128 tile, 256 threads (2x2 waves of 64x64), BK=32.
// Staging via global_load_lds width=16 with XOR swizzle so both the DMA
// (wave-uniform base + lane*16) and the ds_read_b128 fragment reads work:
//   LDS 16B-block J holds tile row m=J>>2, k-block q=(J&3)^((m>>1)&3).
// Fragment read for (m, quad): J = m*4 + (quad ^ ((m>>1)&3)) -> 8 distinct
// 16B positions per 8 lanes within a 128B bank-row => 2-way only (free).
template <bool STORE_BF16>
__global__ __launch_bounds__(256) void gemm_mfma(
    const u16* __restrict__ A,    // [M,K] bf16
    const u16* __restrict__ BT,   // [N,K] bf16
    const float* __restrict__ bias,
    void* __restrict__ C, int M, int N, int K)
{
    __shared__ u16 As[128 * 32];  // 8 KB, swizzled 16B blocks
    __shared__ u16 Bs[128 * 32];

    const int tid = threadIdx.x;
    const int wave = tid >> 6, lane = tid & 63;
    const int col = lane & 15, quad = lane >> 4;
    const int wm = wave >> 1, wn = wave & 1;
    const int row0 = blockIdx.y << 7, col0 = blockIdx.x << 7;

    f32x4 acc[4][4] = {};

    // staging source addresses (block J = is*256 + wave*64 + lane)
    const u16* asrc[2];
    const u16* bsrc[2];
    u16* adst[2];
    u16* bdst[2];
    #pragma unroll
    for (int is = 0; is < 2; ++is) {
        const int J = is * 256 + wave * 64 + lane;
        const int m = J >> 2;
        const int q = (J & 3) ^ ((m >> 1) & 3);
        asrc[is] = A  + (size_t)(row0 + m) * K + q * 8;
        bsrc[is] = BT + (size_t)(col0 + m) * K + q * 8;
        adst[is] = &As[(size_t)(is * 256 + wave * 64) * 8];  // wave-uniform
        bdst[is] = &Bs[(size_t)(is * 256 + wave * 64) * 8];
    }

    for (int kk = 0; kk < K; kk += 32) {
        __syncthreads();   // prior iteration's LDS reads done
        #pragma unroll
        for (int is = 0; is < 2; ++is) {
            __builtin_amdgcn_global_load_lds(
                (const __attribute__((address_space(1))) unsigned int*)(asrc[is] + kk),
                (__attribute__((address_space(3))) unsigned int*)adst[is], 16, 0, 0);
            __builtin_amdgcn_global_load_lds(
                (const __attribute__((address_space(1))) unsigned int*)(bsrc[is] + kk),
                (__attribute__((address_space(3))) unsigned int*)bdst[is], 16, 0, 0);
        }
        __syncthreads();   // compiler drains vmcnt before s_barrier (m97)

        short8 af[4], bf[4];
        #pragma unroll
        for (int i = 0; i < 4; ++i) {
            const int m = wm * 64 + i * 16 + col;
            af[i] = *(const short8*)&As[(m * 4 + (quad ^ ((m >> 1) & 3))) * 8];
        }
        #pragma unroll
        for (int j = 0; j < 4; ++j) {
            const int n = wn * 64 + j * 16 + col;
            bf[j] = *(const short8*)&Bs[(n * 4 + (quad ^ ((n >> 1) & 3))) * 8];
        }
        #pragma unroll
        for (int i = 0; i < 4; ++i)
            #pragma unroll
            for (int j = 0; j < 4; ++j)
                acc[i][j] = __builtin_amdgcn_mfma_f32_16x16x32_bf16(
                    af[i], bf[j], acc[i][j], 0, 0, 0);
    }

    // epilogue: C/D layout col=lane&15, row=quad*4+reg
    #pragma unroll
    for (int j = 0; j < 4; ++j) {
        const int gc = col0 + wn * 64 + j * 16 + col;
        const float bj = bias[gc];
        #pragma unroll
        for (int i = 0; i < 4; ++i) {
            const int gr = row0 + wm * 64 + i * 16 + quad * 4;
            #pragma unroll
            for (int r = 0; r < 4; ++r) {
                const float v = acc[i][j][r] + bj;
                if (STORE_BF16)
                    ((u16*)C)[(size_t)(gr + r) * N + gc] = f2b(v);
                else
                    ((float*)C)[(size_t)(gr + r) * N + gc] = v;
            }
        }
    }
}

// ---------------------------------------------------------------------------
// MFMA flash attention (R3 structure, bf16 qkv in, bf16 vals out).
// Block = (qt, bh): 64-query tile of head (b,h). 4 waves x 16-query strips.
__global__ __launch_bounds__(256) void attn_kernel(
    const u16* __restrict__ qkv, u16* __restrict__ vals)
{
    __shared__ u16 Qs[64 * PAD];   // [q_local][d]
    __shared__ u16 Ks[64 * PAD];   // [k_local][d]
    __shared__ u16 Vt[64 * PAD];   // [d][k_local]  (transposed)
    __shared__ u16 Ps[64 * PAD];   // [q_local][k_local], per-wave strips

    const int tid = threadIdx.x;
    const int wave = tid >> 6, lane = tid & 63;
    const int col = lane & 15, quad = lane >> 4;
    const int qt = blockIdx.x;
    const int bh = blockIdx.y;
    const int b = bh >> 4, h = bh & 15;
    const size_t base = (size_t)b * NS * QLD + (size_t)h * (3 * NHD);

    // ---- stage Q tile (64 x 64 bf16), 16B copies ----
    #pragma unroll
    for (int i = 0; i < 2; ++i) {
        const int blk = tid + i * 256;
        const int row = blk >> 3, c8 = (blk & 7) << 3;
        *(uint4*)&Qs[row * PAD + c8] =
            *(const uint4*)(qkv + base + (size_t)(qt * 64 + row) * QLD + c8);
    }

    short8 aq0, aq1;
    f32x4 accO[4] = {};
    float mrow[4], lrow[4], alpha[4];
    #pragma unroll
    for (int r = 0; r < 4; ++r) { mrow[r] = -1e30f; lrow[r] = 0.f; }

    const int q0 = wave * 16;

    for (int kt = 0; kt <= qt; ++kt) {
        __syncthreads();
        // ---- stage K tile ----
        #pragma unroll
        for (int i = 0; i < 2; ++i) {
            const int blk = tid + i * 256;
            const int row = blk >> 3, c8 = (blk & 7) << 3;
            *(uint4*)&Ks[row * PAD + c8] =
                *(const uint4*)(qkv + base + (size_t)(kt * 64 + row) * QLD + NHD + c8);
        }
        // ---- stage V tile transposed (4x4 register transpose) ----
        {
            const int tx = tid & 15, ty = tid >> 4;
            const int k0 = ty << 2, d0 = tx << 2;
            const u16* vsrc = qkv + base + (size_t)(kt * 64 + k0) * QLD + 2 * NHD + d0;
            ushort4 r0 = *(const ushort4*)(vsrc);
            ushort4 r1 = *(const ushort4*)(vsrc + QLD);
            ushort4 r2 = *(const ushort4*)(vsrc + 2 * QLD);
            ushort4 r3 = *(const ushort4*)(vsrc + 3 * QLD);
            *(ushort4*)&Vt[(d0 + 0) * PAD + k0] = make_ushort4(r0.x, r1.x, r2.x, r3.x);
            *(ushort4*)&Vt[(d0 + 1) * PAD + k0] = make_ushort4(r0.y, r1.y, r2.y, r3.y);
            *(ushort4*)&Vt[(d0 + 2) * PAD + k0] = make_ushort4(r0.z, r1.z, r2.z, r3.z);
            *(ushort4*)&Vt[(d0 + 3) * PAD + k0] = make_ushort4(r0.w, r1.w, r2.w, r3.w);
        }
        __syncthreads();

        if (kt == 0) {
            aq0 = *(const short8*)&Qs[(q0 + col) * PAD + quad * 8];
            aq1 = *(const short8*)&Qs[(q0 + col) * PAD + 32 + quad * 8];
        }

        // ---- S = Q K^T ----
        f32x4 s[4] = {};
        #pragma unroll
        for (int kg = 0; kg < 4; ++kg) {
            short8 b0 = *(const short8*)&Ks[(kg * 16 + col) * PAD + quad * 8];
            short8 b1 = *(const short8*)&Ks[(kg * 16 + col) * PAD + 32 + quad * 8];
            s[kg] = __builtin_amdgcn_mfma_f32_16x16x32_bf16(aq0, b0, s[kg], 0, 0, 0);
            s[kg] = __builtin_amdgcn_mfma_f32_16x16x32_bf16(aq1, b1, s[kg], 0, 0, 0);
        }

        // ---- scale + causal mask (diagonal tile only) ----
        const bool diag = (kt == qt);
        #pragma unroll
        for (int kg = 0; kg < 4; ++kg)
            #pragma unroll
            for (int r = 0; r < 4; ++r) {
                float v = s[kg][r] * 0.125f;
                if (diag && (kg * 16 + col > q0 + quad * 4 + r)) v = -1e30f;
                s[kg][r] = v;
            }

        // ---- online softmax ----
        #pragma unroll
        for (int r = 0; r < 4; ++r) {
            float mx = fmaxf(fmaxf(s[0][r], s[1][r]), fmaxf(s[2][r], s[3][r]));
            mx = fmaxf(mx, __shfl_xor(mx, 1, 64));
            mx = fmaxf(mx, __shfl_xor(mx, 2, 64));
            mx = fmaxf(mx, __shfl_xor(mx, 4, 64));
            mx = fmaxf(mx, __shfl_xor(mx, 8, 64));
            float mn = fmaxf(mrow[r], mx);
            alpha[r] = __expf(mrow[r] - mn);
            mrow[r] = mn;
        }
        #pragma unroll
        for (int r = 0; r < 4; ++r) {
            float ps = 0.f;
            #pragma unroll
            for (int kg = 0; kg < 4; ++kg) {
                float p = __expf(s[kg][r] - mrow[r]);
                ps += p;
                Ps[(q0 + quad * 4 + r) * PAD + kg * 16 + col] = f2b(p);
            }
            ps += __shfl_xor(ps, 1, 64);
            ps += __shfl_xor(ps, 2, 64);
            ps += __shfl_xor(ps, 4, 64);
            ps += __shfl_xor(ps, 8, 64);
            lrow[r] = lrow[r] * alpha[r] + ps;
            #pragma unroll
            for (int dg = 0; dg < 4; ++dg) accO[dg][r] *= alpha[r];
        }

        // ---- O += P V ----
        short8 ap0 = *(const short8*)&Ps[(q0 + col) * PAD + quad * 8];
        short8 ap1 = *(const short8*)&Ps[(q0 + col) * PAD + 32 + quad * 8];
        #pragma unroll
        for (int dg = 0; dg < 4; ++dg) {
            short8 b0 = *(const short8*)&Vt[(dg * 16 + col) * PAD + quad * 8];
            short8 b1 = *(const short8*)&Vt[(dg * 16 + col) * PAD + 32 + quad * 8];
            accO[dg] = __builtin_amdgcn_mfma_f32_16x16x32_bf16(ap0, b0, accO[dg], 0, 0, 0);
            accO[dg] = __builtin_amdgcn_mfma_f32_16x16x32_bf16(ap1, b1, accO[dg], 0, 0, 0);
        }
    }

    // ---- epilogue: vals[b][q][h*64+d] = O / l  (bf16) ----
    #pragma unroll
    for (int r = 0; r < 4; ++r) {
        const float inv = 1.f / lrow[r];
        const size_t rowoff =
            ((size_t)b * NS + qt * 64 + q0 + quad * 4 + r) * ND + h * NHD;
        #pragma unroll
        for (int dg = 0; dg < 4; ++dg)
            vals[rowoff + dg * 16 + col] = f2b(accO[dg][r] * inv);
    }
}

extern "C" void kernel_launch(void* const* d_in, const int* in_sizes, int n_in,
                              void* d_out, int out_size, void* d_ws, size_t ws_size,
                              hipStream_t stream)
{
    // inputs: x, mask(unused), W_qkv, b_qkv, W_o, b_o  -- all fp32
    const float* x    = (const float*)d_in[0];
    const float* Wqkv = (const float*)d_in[2];
    const float* bqkv = (const float*)d_in[3];
    const float* Wo   = (const float*)d_in[4];
    const float* bo   = (const float*)d_in[5];
    float* out = (float*)d_out;

    // bf16 workspace layout (u16 elements):
    u16* x_bf   = (u16*)d_ws;                       //  4096*1024
    u16* WqkvT  = x_bf   + (size_t)4096 * 1024;     //  3072*1024  [N,K]
    u16* WoT    = WqkvT  + (size_t)3072 * 1024;     //  1024*1024  [N,K]
    u16* qkv    = WoT    + (size_t)1024 * 1024;     //  4096*3072
    u16* vals   = qkv    + (size_t)4096 * 3072;     //  4096*1024

    const int M = NB * NS;  // 4096

    convert_bf16<<<dim3(M * ND / (256 * 8)), dim3(256), 0, stream>>>(
        x, x_bf, M * ND);
    transpose_bf16<<<dim3(QLD / 64, ND / 64), dim3(256), 0, stream>>>(
        Wqkv, WqkvT, ND, QLD);
    transpose_bf16<<<dim3(ND / 64, ND / 64), dim3(256), 0, stream>>>(
        Wo, WoT, ND, ND);

    gemm_mfma<true><<<dim3(QLD / 128, M / 128), dim3(256), 0, stream>>>(
        x_bf, WqkvT, bqkv, qkv, M, QLD, ND);
    attn_kernel<<<dim3(NS / 64, NB * NH), dim3(256), 0, stream>>>(qkv, vals);
    gemm_mfma<false><<<dim3(ND / 128, M / 128), dim3(256), 0, stream>>>(
        vals, WoT, bo, out, M, ND, ND);
}

// Round 5
// 237.964 us; speedup vs baseline: 13.7276x; 1.2273x over previous
//
#include <hip/hip_runtime.h>

// Problem constants (B=2, S=2048, D=1024, H=16, HD=64). fp32 in / fp32 out.
#define NB 2
#define NS 2048
#define ND 1024
#define NH 16
#define NHD 64
#define QLD (3 * ND)   // qkv workspace row stride in elements = 3072
#define PADP 72        // Ps row stride (u16)
#define PADV 68        // Vt row stride (u16): balanced 4-way writes, b64 reads

typedef unsigned short u16;
typedef __attribute__((ext_vector_type(8))) short short8;   // 8 x bf16 (4 VGPRs)
typedef __attribute__((ext_vector_type(4))) short short4v;  // 4 x bf16 (2 VGPRs)
typedef __attribute__((ext_vector_type(4))) float f32x4;

__device__ __forceinline__ u16 f2b(float f) {
    unsigned int x = __float_as_uint(f);
    return (u16)((x + 0x7fffu + ((x >> 16) & 1u)) >> 16);  // RNE
}

// ---------------------------------------------------------------------------
// fp32 -> bf16 elementwise cast (for x). n must be a multiple of 8.
__global__ __launch_bounds__(256) void convert_bf16(
    const float* __restrict__ src, u16* __restrict__ dst, int n)
{
    const int i = (blockIdx.x * 256 + threadIdx.x) * 8;
    if (i >= n) return;
    float4 a = *(const float4*)(src + i);
    float4 b = *(const float4*)(src + i + 4);
    *(ushort4*)(dst + i)     = make_ushort4(f2b(a.x), f2b(a.y), f2b(a.z), f2b(a.w));
    *(ushort4*)(dst + i + 4) = make_ushort4(f2b(b.x), f2b(b.y), f2b(b.z), f2b(b.w));
}

// ---------------------------------------------------------------------------
// W[K,N] fp32 -> WT[N,K] bf16 (64x64 tiles via LDS).
__global__ __launch_bounds__(256) void transpose_bf16(
    const float* __restrict__ W, u16* __restrict__ WT, int K, int N)
{
    __shared__ u16 Ts[64 * 72];
    const int t = threadIdx.x;
    const int k0 = blockIdx.y << 6, n0 = blockIdx.x << 6;
    const int r = t >> 4, c = (t & 15) << 2;
    #pragma unroll
    for (int rr = 0; rr < 64; rr += 16) {
        float4 v = *(const float4*)&W[(size_t)(k0 + r + rr) * N + n0 + c];
        Ts[(c + 0) * 72 + r + rr] = f2b(v.x);
        Ts[(c + 1) * 72 + r + rr] = f2b(v.y);
        Ts[(c + 2) * 72 + r + rr] = f2b(v.z);
        Ts[(c + 3) * 72 + r + rr] = f2b(v.w);
    }
    __syncthreads();
    const int n = t >> 2, cc = (t & 3) << 4;
    uint4 a = *(const uint4*)&Ts[n * 72 + cc];
    uint4 b = *(const uint4*)&Ts[n * 72 + cc + 8];
    *(uint4*)&WT[(size_t)(n0 + n) * K + k0 + cc]     = a;
    *(uint4*)&WT[(size_t)(n0 + n) * K + k0 + cc + 8] = b;
}

// ---------------------------------------------------------------------------
// bf16 MFMA GEMM (m97 structure): C[M,N] = A[M,K] @ BT[N,K]^T + bias[N].
// 128x128 tile, 256 threads, BK=32, global_load_lds w=16, XOR swizzle.
template <bool STORE_BF16>
__global__ __launch_bounds__(256) void gemm_mfma(
    const u16* __restrict__ A, const u16* __restrict__ BT,
    const float* __restrict__ bias,
    void* __restrict__ C, int M, int N, int K)
{
    __shared__ u16 As[128 * 32];
    __shared__ u16 Bs[128 * 32];

    const int tid = threadIdx.x;
    const int wave = tid >> 6, lane = tid & 63;
    const int col = lane & 15, quad = lane >> 4;
    const int wm = wave >> 1, wn = wave & 1;
    const int row0 = blockIdx.y << 7, col0 = blockIdx.x << 7;

    f32x4 acc[4][4] = {};

    const u16* asrc[2];
    const u16* bsrc[2];
    u16* adst[2];
    u16* bdst[2];
    #pragma unroll
    for (int is = 0; is < 2; ++is) {
        const int J = is * 256 + wave * 64 + lane;
        const int m = J >> 2;
        const int q = (J & 3) ^ ((m >> 1) & 3);
        asrc[is] = A  + (size_t)(row0 + m) * K + q * 8;
        bsrc[is] = BT + (size_t)(col0 + m) * K + q * 8;
        adst[is] = &As[(size_t)(is * 256 + wave * 64) * 8];
        bdst[is] = &Bs[(size_t)(is * 256 + wave * 64) * 8];
    }

    for (int kk = 0; kk < K; kk += 32) {
        __syncthreads();
        #pragma unroll
        for (int is = 0; is < 2; ++is) {
            __builtin_amdgcn_global_load_lds(
                (const __attribute__((address_space(1))) unsigned int*)(asrc[is] + kk),
                (__attribute__((address_space(3))) unsigned int*)adst[is], 16, 0, 0);
            __builtin_amdgcn_global_load_lds(
                (const __attribute__((address_space(1))) unsigned int*)(bsrc[is] + kk),
                (__attribute__((address_space(3))) unsigned int*)bdst[is], 16, 0, 0);
        }
        __syncthreads();

        short8 af[4], bf[4];
        #pragma unroll
        for (int i = 0; i < 4; ++i) {
            const int m = wm * 64 + i * 16 + col;
            af[i] = *(const short8*)&As[(m * 4 + (quad ^ ((m >> 1) & 3))) * 8];
        }
        #pragma unroll
        for (int j = 0; j < 4; ++j) {
            const int n = wn * 64 + j * 16 + col;
            bf[j] = *(const short8*)&Bs[(n * 4 + (quad ^ ((n >> 1) & 3))) * 8];
        }
        #pragma unroll
        for (int i = 0; i < 4; ++i)
            #pragma unroll
            for (int j = 0; j < 4; ++j)
                acc[i][j] = __builtin_amdgcn_mfma_f32_16x16x32_bf16(
                    af[i], bf[j], acc[i][j], 0, 0, 0);
    }

    #pragma unroll
    for (int j = 0; j < 4; ++j) {
        const int gc = col0 + wn * 64 + j * 16 + col;
        const float bj = bias[gc];
        #pragma unroll
        for (int i = 0; i < 4; ++i) {
            const int gr = row0 + wm * 64 + i * 16 + quad * 4;
            #pragma unroll
            for (int r = 0; r < 4; ++r) {
                const float v = acc[i][j][r] + bj;
                if (STORE_BF16)
                    ((u16*)C)[(size_t)(gr + r) * N + gc] = f2b(v);
                else
                    ((float*)C)[(size_t)(gr + r) * N + gc] = v;
            }
        }
    }
}

// ---------------------------------------------------------------------------
// MFMA flash attention, causal-paired tiles.
// Block = (pair, bh): query tiles qtA=pair, qtB=31-pair of head (b,h); the
// K/V tile staged per kt is shared by both q-tiles -> uniform 33 tile-works.
// Ks: flat 64x64 u16, XOR-swizzled 16B chunks (chunk' = chunk ^ (row&7)),
// staged via global_load_lds w=16 (also used to stage Q at prologue).
// Vt: transposed V, pad 68 (balanced 4-way writes; b64 fragment reads).
__global__ __launch_bounds__(256) void attn_kernel(
    const u16* __restrict__ qkv, u16* __restrict__ vals)
{
    __shared__ u16 Ks[64 * 64];     // 8 KB, swizzled
    __shared__ u16 Vt[64 * PADV];   // 8.5 KB
    __shared__ u16 Ps[64 * PADP];   // 9 KB, per-wave 16-row strips

    const int tid = threadIdx.x;
    const int wave = tid >> 6, lane = tid & 63;
    const int col = lane & 15, quad = lane >> 4;
    const int qtA = blockIdx.x;          // 0..15
    const int qtB = 31 - qtA;            // 16..31
    const int bh = blockIdx.y;
    const int b = bh >> 4, h = bh & 15;
    const size_t base = (size_t)b * NS * QLD + (size_t)h * (3 * NHD);
    const int q0 = wave * 16;

    // DMA block decomposition: J = is*256 + wave*64 + lane; row m=J>>3,
    // stored chunk position c'=J&7 holds source chunk c = c' ^ (m&7).
    int Jrow[2], Jcol[2];
    u16* kdst[2];
    #pragma unroll
    for (int is = 0; is < 2; ++is) {
        const int J = is * 256 + wave * 64 + lane;
        Jrow[is] = J >> 3;
        Jcol[is] = (((J & 7) ^ (Jrow[is] & 7))) << 3;
        kdst[is] = &Ks[(size_t)(is * 256 + wave * 64) * 8];
    }

    auto stage_tile = [&](int srow, int coloff) {
        #pragma unroll
        for (int is = 0; is < 2; ++is) {
            __builtin_amdgcn_global_load_lds(
                (const __attribute__((address_space(1))) unsigned int*)
                    (qkv + base + (size_t)(srow + Jrow[is]) * QLD + coloff + Jcol[is]),
                (__attribute__((address_space(3))) unsigned int*)kdst[is], 16, 0, 0);
        }
    };
    // fragment read from swizzled Ks: row, k-half (0: k=quad*8, 1: k=32+quad*8)
    auto read_frag = [&](int row, int half) -> short8 {
        const int blk = row * 8 + (((quad + (half << 2))) ^ (row & 7));
        return *(const short8*)&Ks[blk << 3];
    };

    // ---- prologue: stage both Q tiles through Ks, hoist A-fragments ----
    stage_tile(qtA * 64, 0);
    __syncthreads();
    short8 aqA0 = read_frag(q0 + col, 0);
    short8 aqA1 = read_frag(q0 + col, 1);
    __syncthreads();
    stage_tile(qtB * 64, 0);
    __syncthreads();
    short8 aqB0 = read_frag(q0 + col, 0);
    short8 aqB1 = read_frag(q0 + col, 1);

    f32x4 accA[4] = {}, accB[4] = {};
    float mA[4], lA[4], mB[4], lB[4];
    #pragma unroll
    for (int r = 0; r < 4; ++r) { mA[r] = mB[r] = -1e30f; lA[r] = lB[r] = 0.f; }

    auto process = [&](const short8& a0, const short8& a1,
                       f32x4* accO, float* mrow, float* lrow, bool diag) {
        // S = Q K^T  (16q x 64k per wave)
        f32x4 s[4] = {};
        #pragma unroll
        for (int kg = 0; kg < 4; ++kg) {
            short8 b0 = read_frag(kg * 16 + col, 0);
            short8 b1 = read_frag(kg * 16 + col, 1);
            s[kg] = __builtin_amdgcn_mfma_f32_16x16x32_bf16(a0, b0, s[kg], 0, 0, 0);
            s[kg] = __builtin_amdgcn_mfma_f32_16x16x32_bf16(a1, b1, s[kg], 0, 0, 0);
        }
        // scale + causal mask (diagonal tile only)
        #pragma unroll
        for (int kg = 0; kg < 4; ++kg)
            #pragma unroll
            for (int r = 0; r < 4; ++r) {
                float v = s[kg][r] * 0.125f;
                if (diag && (kg * 16 + col > q0 + quad * 4 + r)) v = -1e30f;
                s[kg][r] = v;
            }
        // online softmax (rows quad*4+r, reduce over 16-lane groups)
        float alpha[4];
        #pragma unroll
        for (int r = 0; r < 4; ++r) {
            float mx = fmaxf(fmaxf(s[0][r], s[1][r]), fmaxf(s[2][r], s[3][r]));
            mx = fmaxf(mx, __shfl_xor(mx, 1, 64));
            mx = fmaxf(mx, __shfl_xor(mx, 2, 64));
            mx = fmaxf(mx, __shfl_xor(mx, 4, 64));
            mx = fmaxf(mx, __shfl_xor(mx, 8, 64));
            float mn = fmaxf(mrow[r], mx);
            alpha[r] = __expf(mrow[r] - mn);
            mrow[r] = mn;
        }
        #pragma unroll
        for (int r = 0; r < 4; ++r) {
            float ps = 0.f;
            #pragma unroll
            for (int kg = 0; kg < 4; ++kg) {
                float p = __expf(s[kg][r] - mrow[r]);
                ps += p;
                Ps[(q0 + quad * 4 + r) * PADP + kg * 16 + col] = f2b(p);
            }
            ps += __shfl_xor(ps, 1, 64);
            ps += __shfl_xor(ps, 2, 64);
            ps += __shfl_xor(ps, 4, 64);
            ps += __shfl_xor(ps, 8, 64);
            lrow[r] = lrow[r] * alpha[r] + ps;
            #pragma unroll
            for (int dg = 0; dg < 4; ++dg) accO[dg][r] *= alpha[r];
        }
        // O += P V  (per-wave private Ps strip; Vt b64 reads)
        short8 ap0 = *(const short8*)&Ps[(q0 + col) * PADP + quad * 8];
        short8 ap1 = *(const short8*)&Ps[(q0 + col) * PADP + 32 + quad * 8];
        #pragma unroll
        for (int dg = 0; dg < 4; ++dg) {
            const int n = dg * 16 + col;
            short4v lo0 = *(const short4v*)&Vt[n * PADV + quad * 8];
            short4v hi0 = *(const short4v*)&Vt[n * PADV + quad * 8 + 4];
            short4v lo1 = *(const short4v*)&Vt[n * PADV + 32 + quad * 8];
            short4v hi1 = *(const short4v*)&Vt[n * PADV + 32 + quad * 8 + 4];
            short8 b0 = __builtin_shufflevector(lo0, hi0, 0, 1, 2, 3, 4, 5, 6, 7);
            short8 b1 = __builtin_shufflevector(lo1, hi1, 0, 1, 2, 3, 4, 5, 6, 7);
            accO[dg] = __builtin_amdgcn_mfma_f32_16x16x32_bf16(ap0, b0, accO[dg], 0, 0, 0);
            accO[dg] = __builtin_amdgcn_mfma_f32_16x16x32_bf16(ap1, b1, accO[dg], 0, 0, 0);
        }
    };

    for (int kt = 0; kt <= qtB; ++kt) {
        __syncthreads();                 // prior Ks/Vt reads complete
        stage_tile(kt * 64, NHD);        // K tile -> Ks (async DMA)
        {   // V tile -> Vt transposed (4x4 register transpose)
            const int tx = tid & 15, ty = tid >> 4;
            const int k0 = ty << 2, d0 = tx << 2;
            const u16* vsrc = qkv + base + (size_t)(kt * 64 + k0) * QLD + 2 * NHD + d0;
            ushort4 r0 = *(const ushort4*)(vsrc);
            ushort4 r1 = *(const ushort4*)(vsrc + QLD);
            ushort4 r2 = *(const ushort4*)(vsrc + 2 * QLD);
            ushort4 r3 = *(const ushort4*)(vsrc + 3 * QLD);
            *(ushort4*)&Vt[(d0 + 0) * PADV + k0] = make_ushort4(r0.x, r1.x, r2.x, r3.x);
            *(ushort4*)&Vt[(d0 + 1) * PADV + k0] = make_ushort4(r0.y, r1.y, r2.y, r3.y);
            *(ushort4*)&Vt[(d0 + 2) * PADV + k0] = make_ushort4(r0.z, r1.z, r2.z, r3.z);
            *(ushort4*)&Vt[(d0 + 3) * PADV + k0] = make_ushort4(r0.w, r1.w, r2.w, r3.w);
        }
        __syncthreads();                 // DMA + Vt writes visible

        process(aqB0, aqB1, accB, mB, lB, kt == qtB);
        if (kt <= qtA)
            process(aqA0, aqA1, accA, mA, lA, kt == qtA);
    }

    // ---- epilogue: vals[b][q][h*64+d] = O / l  (bf16) ----
    #pragma unroll
    for (int r = 0; r < 4; ++r) {
        const float invA = 1.f / lA[r];
        const float invB = 1.f / lB[r];
        const size_t rowA = ((size_t)b * NS + qtA * 64 + q0 + quad * 4 + r) * ND + h * NHD;
        const size_t rowB = ((size_t)b * NS + qtB * 64 + q0 + quad * 4 + r) * ND + h * NHD;
        #pragma unroll
        for (int dg = 0; dg < 4; ++dg) {
            vals[rowA + dg * 16 + col] = f2b(accA[dg][r] * invA);
            vals[rowB + dg * 16 + col] = f2b(accB[dg][r] * invB);
        }
    }
}

extern "C" void kernel_launch(void* const* d_in, const int* in_sizes, int n_in,
                              void* d_out, int out_size, void* d_ws, size_t ws_size,
                              hipStream_t stream)
{
    // inputs: x, mask(unused), W_qkv, b_qkv, W_o, b_o  -- all fp32
    const float* x    = (const float*)d_in[0];
    const float* Wqkv = (const float*)d_in[2];
    const float* bqkv = (const float*)d_in[3];
    const float* Wo   = (const float*)d_in[4];
    const float* bo   = (const float*)d_in[5];
    float* out = (float*)d_out;

    u16* x_bf   = (u16*)d_ws;                       //  4096*1024
    u16* WqkvT  = x_bf   + (size_t)4096 * 1024;     //  3072*1024  [N,K]
    u16* WoT    = WqkvT  + (size_t)3072 * 1024;     //  1024*1024  [N,K]
    u16* qkv    = WoT    + (size_t)1024 * 1024;     //  4096*3072
    u16* vals   = qkv    + (size_t)4096 * 3072;     //  4096*1024

    const int M = NB * NS;  // 4096

    convert_bf16<<<dim3(M * ND / (256 * 8)), dim3(256), 0, stream>>>(
        x, x_bf, M * ND);
    transpose_bf16<<<dim3(QLD / 64, ND / 64), dim3(256), 0, stream>>>(
        Wqkv, WqkvT, ND, QLD);
    transpose_bf16<<<dim3(ND / 64, ND / 64), dim3(256), 0, stream>>>(
        Wo, WoT, ND, ND);

    gemm_mfma<true><<<dim3(QLD / 128, M / 128), dim3(256), 0, stream>>>(
        x_bf, WqkvT, bqkv, qkv, M, QLD, ND);
    attn_kernel<<<dim3(16, NB * NH), dim3(256), 0, stream>>>(qkv, vals);
    gemm_mfma<false><<<dim3(ND / 128, M / 128), dim3(256), 0, stream>>>(
        vals, WoT, bo, out, M, ND, ND);
}